// Round 4
// baseline (493.721 us; speedup 1.0000x reference)
//
#include <hip/hip_runtime.h>

#define C0 0.28209479177387814f
#define C1 0.4886025119029199f
#define BLK 256

typedef float v4f __attribute__((ext_vector_type(4)));

__device__ __forceinline__ float sigmoidf(float x) {
    return 1.0f / (1.0f + __expf(-x));
}

__device__ __forceinline__ void st_nt(float* p, v4f v) {
    __builtin_nontemporal_store(v, (v4f*)p);
}

// Each thread processes 4 consecutive Gaussians. All per-thread chunks are
// whole aligned float4s: vd/xyz/sl = 3 f4, quat = 4 f4, op = 1 f4, sh = 12 f4,
// cov = 9 f4, rgb = 3 f4. No LDS, no barriers; ~27 independent loads/thread.
__global__ __launch_bounds__(BLK) void gauss_kernel(
    const float* __restrict__ view_dirs,
    const float* __restrict__ xyz,
    const float* __restrict__ scale_log,
    const float* __restrict__ rot_quat,
    const float* __restrict__ opacity_logit,
    const float* __restrict__ sh,
    float* __restrict__ out_xyz,
    float* __restrict__ out_cov,
    float* __restrict__ out_rgb,
    float* __restrict__ out_op,
    int N)
{
    const int g = blockIdx.x * BLK + threadIdx.x;   // group of 4 Gaussians
    const long long base = (long long)g * 4;
    if (base >= N) return;

    if (base + 3 < N) {
        const v4f* vdp = (const v4f*)(view_dirs + base * 3);
        const v4f* xp  = (const v4f*)(xyz       + base * 3);
        const v4f* slp = (const v4f*)(scale_log + base * 3);
        const v4f* qp  = (const v4f*)(rot_quat  + base * 4);
        const v4f* opp = (const v4f*)(opacity_logit + base);
        const v4f* shp = (const v4f*)(sh + base * 12);

        // ---- issue all loads (independent; compiler batches vmcnt) ----
        v4f vdv[3], xv[3], slv[3], qv[4], shv[12], opv;
        #pragma unroll
        for (int k = 0; k < 3; k++)  vdv[k] = vdp[k];
        #pragma unroll
        for (int k = 0; k < 3; k++)  xv[k]  = xp[k];
        #pragma unroll
        for (int k = 0; k < 3; k++)  slv[k] = slp[k];
        #pragma unroll
        for (int k = 0; k < 4; k++)  qv[k]  = qp[k];
        opv = opp[0];
        #pragma unroll
        for (int k = 0; k < 12; k++) shv[k] = shp[k];

        const float* vdf = (const float*)vdv;
        const float* slf = (const float*)slv;
        const float* qf  = (const float*)qv;
        const float* opf = (const float*)&opv;
        const float* shf = (const float*)shv;

        float cov[36], rgb[12], op[4];

        #pragma unroll
        for (int j = 0; j < 4; j++) {
            float vx = vdf[3*j+0], vy = vdf[3*j+1], vz = vdf[3*j+2];

            rgb[3*j+0] = sigmoidf(C0*shf[12*j+0] - C1*vy*shf[12*j+1] + C1*vz*shf[12*j+2]  - C1*vx*shf[12*j+3]);
            rgb[3*j+1] = sigmoidf(C0*shf[12*j+4] - C1*vy*shf[12*j+5] + C1*vz*shf[12*j+6]  - C1*vx*shf[12*j+7]);
            rgb[3*j+2] = sigmoidf(C0*shf[12*j+8] - C1*vy*shf[12*j+9] + C1*vz*shf[12*j+10] - C1*vx*shf[12*j+11]);

            float qr = qf[4*j+0], qx = qf[4*j+1], qy = qf[4*j+2], qz = qf[4*j+3];
            float nrm = sqrtf(qr*qr + qx*qx + qy*qy + qz*qz);
            float inv = 1.0f / fmaxf(nrm, 1e-12f);
            float r = qr*inv, x = qx*inv, y = qy*inv, z = qz*inv;

            float R00 = 1.0f - 2.0f*(y*y + z*z);
            float R01 = 2.0f*(x*y - r*z);
            float R02 = 2.0f*(x*z + r*y);
            float R10 = 2.0f*(x*y + r*z);
            float R11 = 1.0f - 2.0f*(x*x + z*z);
            float R12 = 2.0f*(y*z - r*x);
            float R20 = 2.0f*(x*z - r*y);
            float R21 = 2.0f*(y*z + r*x);
            float R22 = 1.0f - 2.0f*(x*x + y*y);

            float s0 = __expf(slf[3*j+0]);
            float s1 = __expf(slf[3*j+1]);
            float s2 = __expf(slf[3*j+2]);

            float M00 = R00*s0, M01 = R01*s1, M02 = R02*s2;
            float M10 = R10*s0, M11 = R11*s1, M12 = R12*s2;
            float M20 = R20*s0, M21 = R21*s1, M22 = R22*s2;

            float c00 = M00*M00 + M01*M01 + M02*M02;
            float c01 = M00*M10 + M01*M11 + M02*M12;
            float c02 = M00*M20 + M01*M21 + M02*M22;
            float c11 = M10*M10 + M11*M11 + M12*M12;
            float c12 = M10*M20 + M11*M21 + M12*M22;
            float c22 = M20*M20 + M21*M21 + M22*M22;

            cov[9*j+0] = c00; cov[9*j+1] = c01; cov[9*j+2] = c02;
            cov[9*j+3] = c01; cov[9*j+4] = c11; cov[9*j+5] = c12;
            cov[9*j+6] = c02; cov[9*j+7] = c12; cov[9*j+8] = c22;

            op[j] = sigmoidf(opf[j]);
        }

        // ---- stores: all aligned float4, nontemporal ----
        float* oxp = out_xyz + base * 3;
        #pragma unroll
        for (int k = 0; k < 3; k++) st_nt(oxp + 4*k, xv[k]);

        float* ocp = out_cov + base * 9;
        const v4f* cf4 = (const v4f*)cov;
        #pragma unroll
        for (int k = 0; k < 9; k++) st_nt(ocp + 4*k, cf4[k]);

        float* orp = out_rgb + base * 3;
        const v4f* rf4 = (const v4f*)rgb;
        #pragma unroll
        for (int k = 0; k < 3; k++) st_nt(orp + 4*k, rf4[k]);

        st_nt(out_op + base, ((const v4f*)op)[0]);
    } else {
        // scalar tail (dead for N % 4 == 0, kept for generality)
        for (long long i = base; i < N; i++) {
            float vx = view_dirs[3*i+0], vy = view_dirs[3*i+1], vz = view_dirs[3*i+2];
            out_xyz[3*i+0] = xyz[3*i+0];
            out_xyz[3*i+1] = xyz[3*i+1];
            out_xyz[3*i+2] = xyz[3*i+2];

            float r0 = C0*sh[12*i+0] - C1*vy*sh[12*i+1] + C1*vz*sh[12*i+2]  - C1*vx*sh[12*i+3];
            float r1 = C0*sh[12*i+4] - C1*vy*sh[12*i+5] + C1*vz*sh[12*i+6]  - C1*vx*sh[12*i+7];
            float r2 = C0*sh[12*i+8] - C1*vy*sh[12*i+9] + C1*vz*sh[12*i+10] - C1*vx*sh[12*i+11];
            out_rgb[3*i+0] = sigmoidf(r0);
            out_rgb[3*i+1] = sigmoidf(r1);
            out_rgb[3*i+2] = sigmoidf(r2);

            float qr = rot_quat[4*i+0], qx = rot_quat[4*i+1], qy = rot_quat[4*i+2], qz = rot_quat[4*i+3];
            float nrm = sqrtf(qr*qr + qx*qx + qy*qy + qz*qz);
            float inv = 1.0f / fmaxf(nrm, 1e-12f);
            float r = qr*inv, x = qx*inv, y = qy*inv, z = qz*inv;
            float R00 = 1.0f - 2.0f*(y*y + z*z);
            float R01 = 2.0f*(x*y - r*z);
            float R02 = 2.0f*(x*z + r*y);
            float R10 = 2.0f*(x*y + r*z);
            float R11 = 1.0f - 2.0f*(x*x + z*z);
            float R12 = 2.0f*(y*z - r*x);
            float R20 = 2.0f*(x*z - r*y);
            float R21 = 2.0f*(y*z + r*x);
            float R22 = 1.0f - 2.0f*(x*x + y*y);
            float s0 = __expf(scale_log[3*i+0]);
            float s1 = __expf(scale_log[3*i+1]);
            float s2 = __expf(scale_log[3*i+2]);
            float M00 = R00*s0, M01 = R01*s1, M02 = R02*s2;
            float M10 = R10*s0, M11 = R11*s1, M12 = R12*s2;
            float M20 = R20*s0, M21 = R21*s1, M22 = R22*s2;
            float* cp = out_cov + 9*i;
            cp[0] = M00*M00 + M01*M01 + M02*M02;
            cp[1] = M00*M10 + M01*M11 + M02*M12;
            cp[2] = M00*M20 + M01*M21 + M02*M22;
            cp[3] = cp[1];
            cp[4] = M10*M10 + M11*M11 + M12*M12;
            cp[5] = M10*M20 + M11*M21 + M12*M22;
            cp[6] = cp[2];
            cp[7] = cp[5];
            cp[8] = M20*M20 + M21*M21 + M22*M22;

            out_op[i] = sigmoidf(opacity_logit[i]);
        }
    }
}

extern "C" void kernel_launch(void* const* d_in, const int* in_sizes, int n_in,
                              void* d_out, int out_size, void* d_ws, size_t ws_size,
                              hipStream_t stream) {
    const float* view_dirs     = (const float*)d_in[0];
    const float* xyz           = (const float*)d_in[1];
    const float* scale_log     = (const float*)d_in[2];
    const float* rot_quat      = (const float*)d_in[3];
    const float* opacity_logit = (const float*)d_in[4];
    const float* sh            = (const float*)d_in[5];

    int N = in_sizes[4];  // opacity_logit has N elements

    float* out = (float*)d_out;
    float* out_xyz = out;                 // N*3
    float* out_cov = out + (size_t)3 * N; // N*9
    float* out_rgb = out + (size_t)12 * N;// N*3
    float* out_op  = out + (size_t)15 * N;// N

    int ngroups = (N + 3) / 4;
    int grid = (ngroups + BLK - 1) / BLK;
    gauss_kernel<<<grid, BLK, 0, stream>>>(view_dirs, xyz, scale_log, rot_quat,
                                           opacity_logit, sh,
                                           out_xyz, out_cov, out_rgb, out_op, N);
}

// Round 5
// 352.041 us; speedup vs baseline: 1.4025x; 1.4025x over previous
//
#include <hip/hip_runtime.h>

#define C0 0.28209479177387814f
#define C1 0.4886025119029199f
#define BLK 256

typedef float v4f __attribute__((ext_vector_type(4)));

__device__ __forceinline__ float sigmoidf(float x) {
    return 1.0f / (1.0f + __expf(-x));
}

// Each thread processes 4 consecutive Gaussians. All per-thread chunks are
// whole aligned float4s: vd/xyz/sl = 3 f4, quat = 4 f4, op = 1 f4, sh = 12 f4,
// cov = 9 f4, rgb = 3 f4. No LDS, no barriers; ~27 independent loads/thread.
// Stores are REGULAR (through L2): the wave's stores per array cover a
// contiguous region, so L2 write-combines into full lines. (R4's nontemporal
// stores bypassed L2 -> 2.9x write amplification + RMW fetches. Never again.)
__global__ __launch_bounds__(BLK) void gauss_kernel(
    const float* __restrict__ view_dirs,
    const float* __restrict__ xyz,
    const float* __restrict__ scale_log,
    const float* __restrict__ rot_quat,
    const float* __restrict__ opacity_logit,
    const float* __restrict__ sh,
    float* __restrict__ out_xyz,
    float* __restrict__ out_cov,
    float* __restrict__ out_rgb,
    float* __restrict__ out_op,
    int N)
{
    const int g = blockIdx.x * BLK + threadIdx.x;   // group of 4 Gaussians
    const int base = g * 4;
    if (base >= N) return;

    if (base + 3 < N) {
        const v4f* vdp = (const v4f*)(view_dirs + (size_t)base * 3);
        const v4f* xp  = (const v4f*)(xyz       + (size_t)base * 3);
        const v4f* slp = (const v4f*)(scale_log + (size_t)base * 3);
        const v4f* qp  = (const v4f*)(rot_quat  + (size_t)base * 4);
        const v4f* opp = (const v4f*)(opacity_logit + base);
        const v4f* shp = (const v4f*)(sh + (size_t)base * 12);

        // ---- issue all loads (independent; compiler batches vmcnt) ----
        v4f vdv[3], xv[3], slv[3], qv[4], shv[12], opv;
        #pragma unroll
        for (int k = 0; k < 3; k++)  vdv[k] = vdp[k];
        #pragma unroll
        for (int k = 0; k < 3; k++)  xv[k]  = xp[k];
        #pragma unroll
        for (int k = 0; k < 3; k++)  slv[k] = slp[k];
        #pragma unroll
        for (int k = 0; k < 4; k++)  qv[k]  = qp[k];
        opv = opp[0];
        #pragma unroll
        for (int k = 0; k < 12; k++) shv[k] = shp[k];

        const float* vdf = (const float*)vdv;
        const float* slf = (const float*)slv;
        const float* qf  = (const float*)qv;
        const float* opf = (const float*)&opv;
        const float* shf = (const float*)shv;

        float cov[36], rgb[12], op[4];

        #pragma unroll
        for (int j = 0; j < 4; j++) {
            float vx = vdf[3*j+0], vy = vdf[3*j+1], vz = vdf[3*j+2];

            rgb[3*j+0] = sigmoidf(C0*shf[12*j+0] - C1*vy*shf[12*j+1] + C1*vz*shf[12*j+2]  - C1*vx*shf[12*j+3]);
            rgb[3*j+1] = sigmoidf(C0*shf[12*j+4] - C1*vy*shf[12*j+5] + C1*vz*shf[12*j+6]  - C1*vx*shf[12*j+7]);
            rgb[3*j+2] = sigmoidf(C0*shf[12*j+8] - C1*vy*shf[12*j+9] + C1*vz*shf[12*j+10] - C1*vx*shf[12*j+11]);

            float qr = qf[4*j+0], qx = qf[4*j+1], qy = qf[4*j+2], qz = qf[4*j+3];
            float nrm = sqrtf(qr*qr + qx*qx + qy*qy + qz*qz);
            float inv = 1.0f / fmaxf(nrm, 1e-12f);
            float r = qr*inv, x = qx*inv, y = qy*inv, z = qz*inv;

            float R00 = 1.0f - 2.0f*(y*y + z*z);
            float R01 = 2.0f*(x*y - r*z);
            float R02 = 2.0f*(x*z + r*y);
            float R10 = 2.0f*(x*y + r*z);
            float R11 = 1.0f - 2.0f*(x*x + z*z);
            float R12 = 2.0f*(y*z - r*x);
            float R20 = 2.0f*(x*z - r*y);
            float R21 = 2.0f*(y*z + r*x);
            float R22 = 1.0f - 2.0f*(x*x + y*y);

            float s0 = __expf(slf[3*j+0]);
            float s1 = __expf(slf[3*j+1]);
            float s2 = __expf(slf[3*j+2]);

            float M00 = R00*s0, M01 = R01*s1, M02 = R02*s2;
            float M10 = R10*s0, M11 = R11*s1, M12 = R12*s2;
            float M20 = R20*s0, M21 = R21*s1, M22 = R22*s2;

            float c00 = M00*M00 + M01*M01 + M02*M02;
            float c01 = M00*M10 + M01*M11 + M02*M12;
            float c02 = M00*M20 + M01*M21 + M02*M22;
            float c11 = M10*M10 + M11*M11 + M12*M12;
            float c12 = M10*M20 + M11*M21 + M12*M22;
            float c22 = M20*M20 + M21*M21 + M22*M22;

            cov[9*j+0] = c00; cov[9*j+1] = c01; cov[9*j+2] = c02;
            cov[9*j+3] = c01; cov[9*j+4] = c11; cov[9*j+5] = c12;
            cov[9*j+6] = c02; cov[9*j+7] = c12; cov[9*j+8] = c22;

            op[j] = sigmoidf(opf[j]);
        }

        // ---- stores: all aligned float4, through L2 (write-combining) ----
        v4f* oxp = (v4f*)(out_xyz + (size_t)base * 3);
        #pragma unroll
        for (int k = 0; k < 3; k++) oxp[k] = xv[k];

        v4f* ocp = (v4f*)(out_cov + (size_t)base * 9);
        const v4f* cf4 = (const v4f*)cov;
        #pragma unroll
        for (int k = 0; k < 9; k++) ocp[k] = cf4[k];

        v4f* orp = (v4f*)(out_rgb + (size_t)base * 3);
        const v4f* rf4 = (const v4f*)rgb;
        #pragma unroll
        for (int k = 0; k < 3; k++) orp[k] = rf4[k];

        ((v4f*)(out_op + base))[0] = ((const v4f*)op)[0];
    } else {
        // scalar tail (dead for N % 4 == 0, kept for generality)
        for (int i = base; i < N; i++) {
            float vx = view_dirs[3*i+0], vy = view_dirs[3*i+1], vz = view_dirs[3*i+2];
            out_xyz[3*i+0] = xyz[3*i+0];
            out_xyz[3*i+1] = xyz[3*i+1];
            out_xyz[3*i+2] = xyz[3*i+2];

            float r0 = C0*sh[12*i+0] - C1*vy*sh[12*i+1] + C1*vz*sh[12*i+2]  - C1*vx*sh[12*i+3];
            float r1 = C0*sh[12*i+4] - C1*vy*sh[12*i+5] + C1*vz*sh[12*i+6]  - C1*vx*sh[12*i+7];
            float r2 = C0*sh[12*i+8] - C1*vy*sh[12*i+9] + C1*vz*sh[12*i+10] - C1*vx*sh[12*i+11];
            out_rgb[3*i+0] = sigmoidf(r0);
            out_rgb[3*i+1] = sigmoidf(r1);
            out_rgb[3*i+2] = sigmoidf(r2);

            float qr = rot_quat[4*i+0], qx = rot_quat[4*i+1], qy = rot_quat[4*i+2], qz = rot_quat[4*i+3];
            float nrm = sqrtf(qr*qr + qx*qx + qy*qy + qz*qz);
            float inv = 1.0f / fmaxf(nrm, 1e-12f);
            float r = qr*inv, x = qx*inv, y = qy*inv, z = qz*inv;
            float R00 = 1.0f - 2.0f*(y*y + z*z);
            float R01 = 2.0f*(x*y - r*z);
            float R02 = 2.0f*(x*z + r*y);
            float R10 = 2.0f*(x*y + r*z);
            float R11 = 1.0f - 2.0f*(x*x + z*z);
            float R12 = 2.0f*(y*z - r*x);
            float R20 = 2.0f*(x*z - r*y);
            float R21 = 2.0f*(y*z + r*x);
            float R22 = 1.0f - 2.0f*(x*x + y*y);
            float s0 = __expf(scale_log[3*i+0]);
            float s1 = __expf(scale_log[3*i+1]);
            float s2 = __expf(scale_log[3*i+2]);
            float M00 = R00*s0, M01 = R01*s1, M02 = R02*s2;
            float M10 = R10*s0, M11 = R11*s1, M12 = R12*s2;
            float M20 = R20*s0, M21 = R21*s1, M22 = R22*s2;
            float* cp = out_cov + (size_t)9*i;
            cp[0] = M00*M00 + M01*M01 + M02*M02;
            cp[1] = M00*M10 + M01*M11 + M02*M12;
            cp[2] = M00*M20 + M01*M21 + M02*M22;
            cp[3] = cp[1];
            cp[4] = M10*M10 + M11*M11 + M12*M12;
            cp[5] = M10*M20 + M11*M21 + M12*M22;
            cp[6] = cp[2];
            cp[7] = cp[5];
            cp[8] = M20*M20 + M21*M21 + M22*M22;

            out_op[i] = sigmoidf(opacity_logit[i]);
        }
    }
}

extern "C" void kernel_launch(void* const* d_in, const int* in_sizes, int n_in,
                              void* d_out, int out_size, void* d_ws, size_t ws_size,
                              hipStream_t stream) {
    const float* view_dirs     = (const float*)d_in[0];
    const float* xyz           = (const float*)d_in[1];
    const float* scale_log     = (const float*)d_in[2];
    const float* rot_quat      = (const float*)d_in[3];
    const float* opacity_logit = (const float*)d_in[4];
    const float* sh            = (const float*)d_in[5];

    int N = in_sizes[4];  // opacity_logit has N elements

    float* out = (float*)d_out;
    float* out_xyz = out;                 // N*3
    float* out_cov = out + (size_t)3 * N; // N*9
    float* out_rgb = out + (size_t)12 * N;// N*3
    float* out_op  = out + (size_t)15 * N;// N

    int ngroups = (N + 3) / 4;
    int grid = (ngroups + BLK - 1) / BLK;
    gauss_kernel<<<grid, BLK, 0, stream>>>(view_dirs, xyz, scale_log, rot_quat,
                                           opacity_logit, sh,
                                           out_xyz, out_cov, out_rgb, out_op, N);
}